// Round 2
// baseline (367.181 us; speedup 1.0000x reference)
//
#include <hip/hip_runtime.h>

#define NB 32
#define CCH 128
#define HH 56
#define WWD 56
#define HWP (HH*WWD)   // 3136
#define K3C (3*CCH)    // 384
#define SPLITK 8

typedef _Float16 half8 __attribute__((ext_vector_type(8)));
typedef _Float16 half4 __attribute__((ext_vector_type(4)));
typedef float floatx4 __attribute__((ext_vector_type(4)));
typedef float f4u __attribute__((ext_vector_type(4), aligned(4)));  // dword-aligned float4

// ---------------- t8: t8[n,o,p] = sum_c conv_w[o,c]*p5w[c]*x[n,c,roll(p)], all 4 o fused --------
__global__ __launch_bounds__(64) void t8_kernel(const float* __restrict__ x,
                                                const float* __restrict__ conv_w,
                                                const float* __restrict__ p5w,
                                                float* __restrict__ t8) {
    const int n = blockIdx.y;
    const int p = blockIdx.x * 64 + threadIdx.x;
    const int proll = (p >= WWD) ? (p - WWD) : (p + (HH - 1) * WWD);
    const float* xb = x + (size_t)n * CCH * HWP + proll;
    float a0 = 0.f, a1 = 0.f, a2 = 0.f, a3 = 0.f;
#pragma unroll 4
    for (int c = 0; c < CCH; ++c) {
        const float xp = xb[(size_t)c * HWP] * p5w[c];
        a0 += conv_w[c] * xp;
        a1 += conv_w[CCH + c] * xp;
        a2 += conv_w[2 * CCH + c] * xp;
        a3 += conv_w[3 * CCH + c] * xp;
    }
    float* dst = t8 + (size_t)n * 4 * HWP + p;
    dst[0] = a0; dst[HWP] = a1; dst[2 * HWP] = a2; dst[3 * HWP] = a3;
}

// ---------------- GEMM1 (split-K): part[s][n][k][c2] = sum_{p in chunk s} t2[k,p]*t6[c2,p] -------
__global__ __launch_bounds__(256) void gemm1_kernel(const float* __restrict__ x,
                                                    const float* __restrict__ p2w,
                                                    float* __restrict__ part) {
    __shared__ _Float16 As[64 * 72];
    __shared__ _Float16 Bs[64 * 72];

    const int n    = blockIdx.z;
    const int tile = blockIdx.x;            // 0..11
    const int m0   = (tile % 6) * 64;       // k-row base
    const int n0   = (tile / 6) * 64;       // c2 base
    const int s    = blockIdx.y;            // 0..7
    const int i0   = (s * 49) >> 3;         // BK=64 iteration range
    const int i1   = ((s + 1) * 49) >> 3;

    const int tid   = threadIdx.x;
    const int srow  = tid >> 2;             // 0..63
    const int sseg0 = (tid & 3) * 8;        // 0,8,16,24

    // A row: k = 3c+j; t2[k,p] = p2w[k,p]*x[c, p + 112*(j-1)] (zero-pad)
    const int krow = m0 + srow;
    const int ca   = krow / 3;
    const int ja   = krow - ca * 3;
    const float* xa = x + ((size_t)n * CCH + ca) * HWP;
    const float* pw = p2w + (size_t)krow * HWP;
    const int ashift = 112 * (ja - 1);

    // B row: t6[c2,p] = x[c2,p] + x[c2,roll(p)]
    const float* xb = x + ((size_t)n * CCH + (n0 + srow)) * HWP;

    const int wave = tid >> 6;
    const int lane = tid & 63;
    const int l15  = lane & 15;
    const int quad = lane >> 4;
    const int wm   = (wave >> 1) * 32;
    const int wn   = (wave & 1) * 32;

    floatx4 acc00 = {0.f,0.f,0.f,0.f}, acc01 = {0.f,0.f,0.f,0.f};
    floatx4 acc10 = {0.f,0.f,0.f,0.f}, acc11 = {0.f,0.f,0.f,0.f};

    for (int it = i0; it < i1; ++it) {
        const int p0 = it * 64;
#pragma unroll
        for (int hf = 0; hf < 2; ++hf) {
            const int sseg = sseg0 + hf * 32;
            const int pA = p0 + sseg;
            // ---- stage A ----
            {
                half8 av;
                const int srcp = pA + ashift;   // 8-aligned run: wholly in or out of bounds
                if (srcp >= 0 && srcp < HWP) {
                    const float4 x0 = *(const float4*)(xa + srcp);
                    const float4 x1 = *(const float4*)(xa + srcp + 4);
                    const float4 w0 = *(const float4*)(pw + pA);
                    const float4 w1 = *(const float4*)(pw + pA + 4);
                    av[0] = (_Float16)(x0.x * w0.x); av[1] = (_Float16)(x0.y * w0.y);
                    av[2] = (_Float16)(x0.z * w0.z); av[3] = (_Float16)(x0.w * w0.w);
                    av[4] = (_Float16)(x1.x * w1.x); av[5] = (_Float16)(x1.y * w1.y);
                    av[6] = (_Float16)(x1.z * w1.z); av[7] = (_Float16)(x1.w * w1.w);
                } else {
#pragma unroll
                    for (int i = 0; i < 8; ++i) av[i] = (_Float16)0.f;
                }
                *(half8*)(&As[srow * 72 + sseg]) = av;
            }
            // ---- stage B ----
            {
                const int h = pA / WWD;        // 8-run never crosses an h row
                const int proll = (h >= 1) ? (pA - WWD) : (pA + (HH - 1) * WWD);
                const float4 u0 = *(const float4*)(xb + pA);
                const float4 u1 = *(const float4*)(xb + pA + 4);
                const float4 v0 = *(const float4*)(xb + proll);
                const float4 v1 = *(const float4*)(xb + proll + 4);
                half8 bv;
                bv[0] = (_Float16)(u0.x + v0.x); bv[1] = (_Float16)(u0.y + v0.y);
                bv[2] = (_Float16)(u0.z + v0.z); bv[3] = (_Float16)(u0.w + v0.w);
                bv[4] = (_Float16)(u1.x + v1.x); bv[5] = (_Float16)(u1.y + v1.y);
                bv[6] = (_Float16)(u1.z + v1.z); bv[7] = (_Float16)(u1.w + v1.w);
                *(half8*)(&Bs[srow * 72 + sseg]) = bv;
            }
        }
        __syncthreads();
#pragma unroll
        for (int ks = 0; ks < 2; ++ks) {
            const int ko = ks * 32 + quad * 8;
            half8 a0 = *(half8*)(&As[(wm + l15) * 72 + ko]);
            half8 a1 = *(half8*)(&As[(wm + 16 + l15) * 72 + ko]);
            half8 b0 = *(half8*)(&Bs[(wn + l15) * 72 + ko]);
            half8 b1 = *(half8*)(&Bs[(wn + 16 + l15) * 72 + ko]);
            acc00 = __builtin_amdgcn_mfma_f32_16x16x32_f16(a0, b0, acc00, 0, 0, 0);
            acc01 = __builtin_amdgcn_mfma_f32_16x16x32_f16(a0, b1, acc01, 0, 0, 0);
            acc10 = __builtin_amdgcn_mfma_f32_16x16x32_f16(a1, b0, acc10, 0, 0, 0);
            acc11 = __builtin_amdgcn_mfma_f32_16x16x32_f16(a1, b1, acc11, 0, 0, 0);
        }
        __syncthreads();
    }

    // fp32 partial store: part[((s*NB+n)*K3C + k)*CCH + c2]; lanes (c2=l15) contiguous
    float* pbase = part + (size_t)(s * NB + n) * K3C * CCH;
    floatx4 accs[2][2] = {{acc00, acc01}, {acc10, acc11}};
#pragma unroll
    for (int mi = 0; mi < 2; ++mi)
#pragma unroll
        for (int ni = 0; ni < 2; ++ni) {
            const int kr = m0 + wm + mi * 16 + quad * 4;
            const int cc = n0 + wn + ni * 16 + l15;
#pragma unroll
            for (int r = 0; r < 4; ++r)
                pbase[(size_t)(kr + r) * CCH + cc] = accs[mi][ni][r];
        }
}

// ---------------- reduce: t7T[n][c2][k] = (1/56) * sum_s part[s][n][k][c2]  (f16, transposed) ----
__global__ __launch_bounds__(256) void reduce_kernel(const float* __restrict__ part,
                                                     _Float16* __restrict__ t7T) {
    __shared__ _Float16 tile[16][130];
    const int n  = blockIdx.y;
    const int k0 = blockIdx.x * 16;
    const int t  = threadIdx.x;
    const int c2 = t & 127;
    const int kh = t >> 7;                   // 0..1
#pragma unroll
    for (int kk = 0; kk < 8; ++kk) {
        const int k = kh * 8 + kk;
        float sum = 0.f;
#pragma unroll
        for (int sp = 0; sp < SPLITK; ++sp)
            sum += part[(((size_t)sp * NB + n) * K3C + k0 + k) * CCH + c2];
        tile[k][c2] = (_Float16)(sum * (1.0f / 56.0f));
    }
    __syncthreads();
    const int kt = t & 15;
    const int c0 = t >> 4;                   // 0..15
#pragma unroll
    for (int cc = 0; cc < 8; ++cc) {
        const int cw = c0 * 8 + cc;
        t7T[((size_t)n * CCH + cw) * K3C + k0 + kt] = tile[kt][cw];
    }
}

// ---------------- GEMM2: out[n,c2,p] = t8[n,c2&3,p]*x[n,c2,p] + (1/sqrt(384)) sum_k t7T[c2,k]*t3[k,p]
__global__ __launch_bounds__(256) void gemm2_kernel(const float* __restrict__ x,
                                                    const _Float16* __restrict__ t7T,
                                                    const float* __restrict__ t8,
                                                    float* __restrict__ out) {
    __shared__ _Float16 As[64 * 72];   // [c2_local][k_local]
    __shared__ _Float16 Bs[64 * 72];   // [p_local][k_local]

    const int n   = blockIdx.z;
    const int pt0 = blockIdx.x * 64;
    const int m0  = blockIdx.y * 64;
    const int tid = threadIdx.x;

    // A staging: row = c2, two half8 segments per thread
    const int arow = tid >> 2;
    const int aseg = (tid & 3) * 8;
    const _Float16* asrc = t7T + ((size_t)n * CCH + (m0 + arow)) * K3C;

    // B staging: 4k x 4p per thread
    const int kb = (tid & 15) * 4;          // k_local base
    const int pb = (tid >> 4) * 4;          // p_local base
    const int pg = pt0 + pb;
    const int hB = pg / WWD;                // 4-run shares h (56%4==0)
    const int w0 = pg - hB * WWD;
    const float* xnh = x + (size_t)n * CCH * HWP + hB * WWD;

    const int wave = tid >> 6;
    const int lane = tid & 63;
    const int l15  = lane & 15;
    const int quad = lane >> 4;
    const int wm   = (wave >> 1) * 32;
    const int wn   = (wave & 1) * 32;

    floatx4 acc00 = {0.f,0.f,0.f,0.f}, acc01 = {0.f,0.f,0.f,0.f};
    floatx4 acc10 = {0.f,0.f,0.f,0.f}, acc11 = {0.f,0.f,0.f,0.f};

    for (int k0 = 0; k0 < K3C; k0 += 64) {
        // ---- stage A ----
        *(half8*)(&As[arow * 72 + aseg])      = *(const half8*)(asrc + k0 + aseg);
        *(half8*)(&As[arow * 72 + aseg + 32]) = *(const half8*)(asrc + k0 + aseg + 32);
        // ---- stage B: t3[k,p] = x[c, h, w + 2j - 2], zero-pad in w ----
        {
            float vals[4][4];
#pragma unroll
            for (int kk = 0; kk < 4; ++kk) {
                const int k = k0 + kb + kk;
                const int c = k / 3;
                const int j = k - c * 3;
                const int lo = w0 + 2 * j - 2;
                const float* row = xnh + (size_t)c * HWP;
                if (lo >= 0 && lo + 3 < WWD) {
                    const f4u v = *(const f4u*)(row + lo);
                    vals[kk][0] = v.x; vals[kk][1] = v.y; vals[kk][2] = v.z; vals[kk][3] = v.w;
                } else {
#pragma unroll
                    for (int pp = 0; pp < 4; ++pp) {
                        const int w = lo + pp;
                        vals[kk][pp] = (w >= 0 && w < WWD) ? row[w] : 0.f;
                    }
                }
            }
#pragma unroll
            for (int pp = 0; pp < 4; ++pp) {
                half4 col;
                col[0] = (_Float16)vals[0][pp]; col[1] = (_Float16)vals[1][pp];
                col[2] = (_Float16)vals[2][pp]; col[3] = (_Float16)vals[3][pp];
                *(half4*)(&Bs[(pb + pp) * 72 + kb]) = col;
            }
        }
        __syncthreads();
#pragma unroll
        for (int ks = 0; ks < 2; ++ks) {
            const int ko = ks * 32 + quad * 8;
            half8 a0 = *(half8*)(&As[(wm + l15) * 72 + ko]);
            half8 a1 = *(half8*)(&As[(wm + 16 + l15) * 72 + ko]);
            half8 b0 = *(half8*)(&Bs[(wn + l15) * 72 + ko]);
            half8 b1 = *(half8*)(&Bs[(wn + 16 + l15) * 72 + ko]);
            acc00 = __builtin_amdgcn_mfma_f32_16x16x32_f16(a0, b0, acc00, 0, 0, 0);
            acc01 = __builtin_amdgcn_mfma_f32_16x16x32_f16(a0, b1, acc01, 0, 0, 0);
            acc10 = __builtin_amdgcn_mfma_f32_16x16x32_f16(a1, b0, acc10, 0, 0, 0);
            acc11 = __builtin_amdgcn_mfma_f32_16x16x32_f16(a1, b1, acc11, 0, 0, 0);
        }
        __syncthreads();
    }

    const float sc = 0.05103103630798288f;  // 1/sqrt(384)
    floatx4 accs[2][2] = {{acc00, acc01}, {acc10, acc11}};
#pragma unroll
    for (int mi = 0; mi < 2; ++mi)
#pragma unroll
        for (int ni = 0; ni < 2; ++ni) {
            const int ccb = m0 + wm + mi * 16 + quad * 4;
            const int pp  = pt0 + wn + ni * 16 + l15;
#pragma unroll
            for (int r = 0; r < 4; ++r) {
                const int c2 = ccb + r;
                const size_t oidx = ((size_t)n * CCH + c2) * HWP + pp;
                const float t9 = t8[((size_t)n * 4 + (c2 & 3)) * HWP + pp] * x[oidx];
                out[oidx] = accs[mi][ni][r] * sc + t9;
            }
        }
}

extern "C" void kernel_launch(void* const* d_in, const int* in_sizes, int n_in,
                              void* d_out, int out_size, void* d_ws, size_t ws_size,
                              hipStream_t stream) {
    const float* x      = (const float*)d_in[0];
    const float* p2w    = (const float*)d_in[1];
    const float* p5w    = (const float*)d_in[2];
    const float* conv_w = (const float*)d_in[3];
    float* out = (float*)d_out;

    // ws: t8 fp32 (1.6 MB) + t7T f16 (3.1 MB). Split-K partials live in d_out
    // (12.58M f32 <= 12.85M) and are fully consumed by reduce before gemm2 writes out.
    float*    t8f  = (float*)d_ws;
    _Float16* t7T  = (_Float16*)((char*)d_ws + (size_t)NB * 4 * HWP * sizeof(float));
    float*    part = out;

    t8_kernel<<<dim3(49, NB), dim3(64), 0, stream>>>(x, conv_w, p5w, t8f);
    gemm1_kernel<<<dim3(12, SPLITK, NB), dim3(256), 0, stream>>>(x, p2w, part);
    reduce_kernel<<<dim3(24, NB), dim3(256), 0, stream>>>(part, t7T);
    gemm2_kernel<<<dim3(49, 2, NB), dim3(256), 0, stream>>>(x, t7T, t8f, out);
}

// Round 3
// 283.797 us; speedup vs baseline: 1.2938x; 1.2938x over previous
//
#include <hip/hip_runtime.h>

#define NB 32
#define CCH 128
#define HH 56
#define WWD 56
#define HWP (HH*WWD)   // 3136
#define K3C (3*CCH)    // 384
#define SPLITK 8

typedef _Float16 half8 __attribute__((ext_vector_type(8)));
typedef _Float16 half4 __attribute__((ext_vector_type(4)));
typedef _Float16 h4u __attribute__((ext_vector_type(4), aligned(4)));
typedef float floatx4 __attribute__((ext_vector_type(4)));

// ---------------- prep: f32 -> f16 copies ----------------
__global__ __launch_bounds__(256) void cvt_kernel(const float* __restrict__ src,
                                                  _Float16* __restrict__ dst) {
    const size_t i = ((size_t)blockIdx.x * 256 + threadIdx.x) * 8;
    const float4 a = *(const float4*)(src + i);
    const float4 b = *(const float4*)(src + i + 4);
    half8 v;
    v[0] = (_Float16)a.x; v[1] = (_Float16)a.y; v[2] = (_Float16)a.z; v[3] = (_Float16)a.w;
    v[4] = (_Float16)b.x; v[5] = (_Float16)b.y; v[6] = (_Float16)b.z; v[7] = (_Float16)b.w;
    *(half8*)(dst + i) = v;
}

// ---------------- t8: t8[n,o,p] = sum_c conv_w[o,c]*p5w[c]*x[n,c,roll(p)] ----------------
__global__ __launch_bounds__(64) void t8_kernel(const _Float16* __restrict__ xh,
                                                const float* __restrict__ conv_w,
                                                const float* __restrict__ p5w,
                                                float* __restrict__ t8) {
    const int n = blockIdx.y;
    const int p = blockIdx.x * 64 + threadIdx.x;
    const int proll = (p >= WWD) ? (p - WWD) : (p + (HH - 1) * WWD);
    const _Float16* xb = xh + (size_t)n * CCH * HWP + proll;
    float a0 = 0.f, a1 = 0.f, a2 = 0.f, a3 = 0.f;
#pragma unroll 4
    for (int c = 0; c < CCH; ++c) {
        const float xp = (float)xb[(size_t)c * HWP] * p5w[c];
        a0 += conv_w[c] * xp;
        a1 += conv_w[CCH + c] * xp;
        a2 += conv_w[2 * CCH + c] * xp;
        a3 += conv_w[3 * CCH + c] * xp;
    }
    float* dst = t8 + (size_t)n * 4 * HWP + p;
    dst[0] = a0; dst[HWP] = a1; dst[2 * HWP] = a2; dst[3 * HWP] = a3;
}

// ---------------- GEMM1 (split-K): part[s][n][k][c2] = sum_{p in chunk} t2[k,p]*t6[c2,p] ----
// Tm=128 (m0 = bx*128), Tn=128 (all c2), BK=64; 4 waves each 64x64.
__global__ __launch_bounds__(256) void gemm1_kernel(const _Float16* __restrict__ xh,
                                                    const _Float16* __restrict__ p2wh,
                                                    float* __restrict__ part) {
    __shared__ _Float16 As[128 * 72];
    __shared__ _Float16 Bs[128 * 72];

    const int n  = blockIdx.z;
    const int m0 = blockIdx.x * 128;        // k base (0,128,256)
    const int s  = blockIdx.y;              // split 0..7
    const int i0 = (s * 49) >> 3;
    const int i1 = ((s + 1) * 49) >> 3;

    const int tid = threadIdx.x;
    const int r   = tid >> 1;               // 0..127 (row for both A and B staging)
    const int c0  = (tid & 1) * 32;         // col base (4 half8 segs)

    // A row: k = m0 + r = 3c+j; t2[k,p] = p2w[k,p]*x[c, p+112*(j-1)]
    const int k   = m0 + r;
    const int ca  = k / 3;
    const int ja  = k - ca * 3;
    const int ashift = 112 * (ja - 1);
    const _Float16* xa = xh + ((size_t)n * CCH + ca) * HWP;
    const _Float16* pw = p2wh + (size_t)k * HWP;
    // B row: t6[c2,p] = x[c2,p] + x[c2,roll(p)]
    const _Float16* xb = xh + ((size_t)n * CCH + r) * HWP;

    const int wave = tid >> 6;
    const int lane = tid & 63;
    const int l15  = lane & 15;
    const int quad = lane >> 4;
    const int wm   = (wave >> 1) * 64;
    const int wn   = (wave & 1) * 64;

    floatx4 acc[4][4];
#pragma unroll
    for (int a = 0; a < 4; ++a)
#pragma unroll
        for (int b = 0; b < 4; ++b) acc[a][b] = (floatx4){0.f,0.f,0.f,0.f};

    for (int it = i0; it < i1; ++it) {
        const int p0 = it * 64;
#pragma unroll
        for (int seg = 0; seg < 4; ++seg) {
            const int col = c0 + seg * 8;
            const int pA  = p0 + col;
            // A
            {
                const int srcp = pA + ashift;  // 8-aligned run: wholly in/out of bounds
                half8 prod;
                if (srcp >= 0 && srcp < HWP) {
                    const half8 xv = *(const half8*)(xa + srcp);
                    const half8 wv = *(const half8*)(pw + pA);
                    prod = xv * wv;            // v_pk_mul_f16
                } else {
#pragma unroll
                    for (int i = 0; i < 8; ++i) prod[i] = (_Float16)0.f;
                }
                *(half8*)(&As[r * 72 + col]) = prod;
            }
            // B
            {
                const int proll = (pA >= WWD) ? (pA - WWD) : (pA + (HH - 1) * WWD);
                const half8 u = *(const half8*)(xb + pA);
                const half8 v = *(const half8*)(xb + proll);
                *(half8*)(&Bs[r * 72 + col]) = u + v;  // v_pk_add_f16
            }
        }
        __syncthreads();
#pragma unroll
        for (int ks = 0; ks < 2; ++ks) {
            const int ko = ks * 32 + quad * 8;
            half8 af[4], bf[4];
#pragma unroll
            for (int mi = 0; mi < 4; ++mi) af[mi] = *(half8*)(&As[(wm + mi * 16 + l15) * 72 + ko]);
#pragma unroll
            for (int ni = 0; ni < 4; ++ni) bf[ni] = *(half8*)(&Bs[(wn + ni * 16 + l15) * 72 + ko]);
#pragma unroll
            for (int mi = 0; mi < 4; ++mi)
#pragma unroll
                for (int ni = 0; ni < 4; ++ni)
                    acc[mi][ni] = __builtin_amdgcn_mfma_f32_16x16x32_f16(af[mi], bf[ni], acc[mi][ni], 0, 0, 0);
        }
        __syncthreads();
    }

    float* pbase = part + (size_t)(s * NB + n) * K3C * CCH;
#pragma unroll
    for (int mi = 0; mi < 4; ++mi)
#pragma unroll
        for (int ni = 0; ni < 4; ++ni) {
            const int kr = m0 + wm + mi * 16 + quad * 4;
            const int cc = wn + ni * 16 + l15;
#pragma unroll
            for (int r2 = 0; r2 < 4; ++r2)
                pbase[(size_t)(kr + r2) * CCH + cc] = acc[mi][ni][r2];
        }
}

// ---------------- reduce: t7T[n][c2][k] = (1/56) * sum_s part[s][n][k][c2] ----------------
__global__ __launch_bounds__(256) void reduce_kernel(const float* __restrict__ part,
                                                     _Float16* __restrict__ t7T) {
    __shared__ _Float16 tile[16][130];
    const int n  = blockIdx.y;
    const int k0 = blockIdx.x * 16;
    const int t  = threadIdx.x;
    const int c2 = t & 127;
    const int kh = t >> 7;
#pragma unroll
    for (int kk = 0; kk < 8; ++kk) {
        const int k = kh * 8 + kk;
        float sum = 0.f;
#pragma unroll
        for (int sp = 0; sp < SPLITK; ++sp)
            sum += part[(((size_t)sp * NB + n) * K3C + k0 + k) * CCH + c2];
        tile[k][c2] = (_Float16)(sum * (1.0f / 56.0f));
    }
    __syncthreads();
    const int kt = t & 15;
    const int c0 = t >> 4;
#pragma unroll
    for (int cc = 0; cc < 8; ++cc) {
        const int cw = c0 * 8 + cc;
        t7T[((size_t)n * CCH + cw) * K3C + k0 + kt] = tile[kt][cw];
    }
}

// ---------------- GEMM2: out[n,c2,p] = t8*x + (1/sqrt(384)) sum_k t7T[c2,k]*t3[k,p] ----------
// Tm=128 (all c2), Tn=64 p; 4 waves each 64x32; BK=64, 6 iters.
__global__ __launch_bounds__(256) void gemm2_kernel(const _Float16* __restrict__ xh,
                                                    const _Float16* __restrict__ t7T,
                                                    const float* __restrict__ t8,
                                                    float* __restrict__ out) {
    __shared__ _Float16 As[128 * 72];   // [c2][k]
    __shared__ _Float16 Bs[64 * 72];    // [p][k]

    const int n   = blockIdx.y;
    const int pt0 = blockIdx.x * 64;
    const int tid = threadIdx.x;

    // A staging: row = c2 (0..127), 4 half8 at col base (tid&1)*32
    const int ar = tid >> 1;
    const int ac = (tid & 1) * 32;
    const _Float16* asrc = t7T + ((size_t)n * CCH + ar) * K3C;

    // B staging: 4k x 4p per thread
    const int kb = (tid & 15) * 4;
    const int pb = (tid >> 4) * 4;
    const int pg = pt0 + pb;
    const int hB = pg / WWD;
    const int w0 = pg - hB * WWD;       // even
    const _Float16* xnh = xh + (size_t)n * CCH * HWP + hB * WWD;

    const int wave = tid >> 6;
    const int lane = tid & 63;
    const int l15  = lane & 15;
    const int quad = lane >> 4;
    const int wm   = (wave >> 1) * 64;
    const int wn   = (wave & 1) * 32;

    floatx4 acc[4][2];
#pragma unroll
    for (int a = 0; a < 4; ++a)
#pragma unroll
        for (int b = 0; b < 2; ++b) acc[a][b] = (floatx4){0.f,0.f,0.f,0.f};

    for (int k0 = 0; k0 < K3C; k0 += 64) {
        // A
#pragma unroll
        for (int seg = 0; seg < 4; ++seg)
            *(half8*)(&As[ar * 72 + ac + seg * 8]) = *(const half8*)(asrc + k0 + ac + seg * 8);
        // B: t3[k,p] = x[c, h, w + 2j - 2], zero-pad in w
        {
            _Float16 vals[4][4];
#pragma unroll
            for (int kk = 0; kk < 4; ++kk) {
                const int k = k0 + kb + kk;
                const int c = k / 3;
                const int j = k - c * 3;
                const int lo = w0 + 2 * j - 2;   // even
                const _Float16* row = xnh + (size_t)c * HWP;
                if (lo >= 0 && lo + 3 < WWD) {
                    const h4u v = *(const h4u*)(row + lo);
                    vals[kk][0] = v[0]; vals[kk][1] = v[1]; vals[kk][2] = v[2]; vals[kk][3] = v[3];
                } else {
#pragma unroll
                    for (int pp = 0; pp < 4; ++pp) {
                        const int w = lo + pp;
                        vals[kk][pp] = (w >= 0 && w < WWD) ? row[w] : (_Float16)0.f;
                    }
                }
            }
#pragma unroll
            for (int pp = 0; pp < 4; ++pp) {
                half4 col;
                col[0] = vals[0][pp]; col[1] = vals[1][pp];
                col[2] = vals[2][pp]; col[3] = vals[3][pp];
                *(half4*)(&Bs[(pb + pp) * 72 + kb]) = col;
            }
        }
        __syncthreads();
#pragma unroll
        for (int ks = 0; ks < 2; ++ks) {
            const int ko = ks * 32 + quad * 8;
            half8 af[4], bf[2];
#pragma unroll
            for (int mi = 0; mi < 4; ++mi) af[mi] = *(half8*)(&As[(wm + mi * 16 + l15) * 72 + ko]);
#pragma unroll
            for (int ni = 0; ni < 2; ++ni) bf[ni] = *(half8*)(&Bs[(wn + ni * 16 + l15) * 72 + ko]);
#pragma unroll
            for (int mi = 0; mi < 4; ++mi)
#pragma unroll
                for (int ni = 0; ni < 2; ++ni)
                    acc[mi][ni] = __builtin_amdgcn_mfma_f32_16x16x32_f16(af[mi], bf[ni], acc[mi][ni], 0, 0, 0);
        }
        __syncthreads();
    }

    const float sc = 0.05103103630798288f;  // 1/sqrt(384)
#pragma unroll
    for (int mi = 0; mi < 4; ++mi)
#pragma unroll
        for (int ni = 0; ni < 2; ++ni) {
            const int ccb = wm + mi * 16 + quad * 4;
            const int pp  = pt0 + wn + ni * 16 + l15;
#pragma unroll
            for (int r2 = 0; r2 < 4; ++r2) {
                const int c2 = ccb + r2;
                const size_t oidx = ((size_t)n * CCH + c2) * HWP + pp;
                const float t9 = t8[((size_t)n * 4 + (c2 & 3)) * HWP + pp] * (float)xh[oidx];
                out[oidx] = acc[mi][ni][r2] * sc + t9;
            }
        }
}

extern "C" void kernel_launch(void* const* d_in, const int* in_sizes, int n_in,
                              void* d_out, int out_size, void* d_ws, size_t ws_size,
                              hipStream_t stream) {
    const float* x      = (const float*)d_in[0];
    const float* p2w    = (const float*)d_in[1];
    const float* p5w    = (const float*)d_in[2];
    const float* conv_w = (const float*)d_in[3];
    float* out = (float*)d_out;

    // ws layout: x_h (25.69 MB) | p2w_h (2.41 MB) | t8 f32 (1.61 MB) | t7T f16 (3.15 MB)
    char* ws = (char*)d_ws;
    _Float16* xh   = (_Float16*)ws;                                   // 12,845,056 f16
    _Float16* p2wh = (_Float16*)(ws + 25690112);                      // 1,204,224 f16
    float*    t8f  = (float*)   (ws + 25690112 + 2408448);            // 401,408 f32
    _Float16* t7T  = (_Float16*)(ws + 25690112 + 2408448 + 1605632);  // 1,572,864 f16
    float*    part = out;  // 12.58M f32 <= 12.85M; consumed by reduce before gemm2 writes

    cvt_kernel<<<dim3(6272), dim3(256), 0, stream>>>(x, xh);       // 6272*256*8 = 12,845,056
    cvt_kernel<<<dim3(588), dim3(256), 0, stream>>>(p2w, p2wh);    // 588*256*8  = 1,204,224
    t8_kernel<<<dim3(49, NB), dim3(64), 0, stream>>>(xh, conv_w, p5w, t8f);
    gemm1_kernel<<<dim3(3, SPLITK, NB), dim3(256), 0, stream>>>(xh, p2wh, part);
    reduce_kernel<<<dim3(24, NB), dim3(256), 0, stream>>>(part, t7T);
    gemm2_kernel<<<dim3(49, NB), dim3(256), 0, stream>>>(xh, t7T, t8f, out);
}

// Round 4
// 246.635 us; speedup vs baseline: 1.4888x; 1.1507x over previous
//
#include <hip/hip_runtime.h>

#define NB 32
#define CCH 128
#define HH 56
#define WWD 56
#define HWP (HH*WWD)   // 3136
#define K3C (3*CCH)    // 384
#define SPLITK 8

typedef _Float16 half8 __attribute__((ext_vector_type(8)));
typedef _Float16 half4 __attribute__((ext_vector_type(4)));
typedef _Float16 h4u __attribute__((ext_vector_type(4), aligned(4)));
typedef float floatx4 __attribute__((ext_vector_type(4)));

// ---------------- prep: f32 -> f16 copies ----------------
__global__ __launch_bounds__(256) void cvt_kernel(const float* __restrict__ src,
                                                  _Float16* __restrict__ dst) {
    const size_t i = ((size_t)blockIdx.x * 256 + threadIdx.x) * 8;
    const float4 a = *(const float4*)(src + i);
    const float4 b = *(const float4*)(src + i + 4);
    half8 v;
    v[0] = (_Float16)a.x; v[1] = (_Float16)a.y; v[2] = (_Float16)a.z; v[3] = (_Float16)a.w;
    v[4] = (_Float16)b.x; v[5] = (_Float16)b.y; v[6] = (_Float16)b.z; v[7] = (_Float16)b.w;
    *(half8*)(dst + i) = v;
}

// ---------------- t8: t8[n,o,p] = sum_c conv_w[o,c]*p5w[c]*x[n,c,roll(p)] ----------------
// 1D grid 1568; XCD swizzle: n % 8 == bid % 8
__global__ __launch_bounds__(64) void t8_kernel(const _Float16* __restrict__ xh,
                                                const float* __restrict__ conv_w,
                                                const float* __restrict__ p5w,
                                                float* __restrict__ t8) {
    const int bid = blockIdx.x;
    const int r8  = bid & 7;
    const int g   = bid >> 3;               // 0..195
    const int n   = r8 + 8 * (g / 49);
    const int pt  = g % 49;
    const int p   = pt * 64 + threadIdx.x;
    const int proll = (p >= WWD) ? (p - WWD) : (p + (HH - 1) * WWD);
    const _Float16* xb = xh + (size_t)n * CCH * HWP + proll;
    float a0 = 0.f, a1 = 0.f, a2 = 0.f, a3 = 0.f;
#pragma unroll 4
    for (int c = 0; c < CCH; ++c) {
        const float xp = (float)xb[(size_t)c * HWP] * p5w[c];
        a0 += conv_w[c] * xp;
        a1 += conv_w[CCH + c] * xp;
        a2 += conv_w[2 * CCH + c] * xp;
        a3 += conv_w[3 * CCH + c] * xp;
    }
    float* dst = t8 + (size_t)n * 4 * HWP + p;
    dst[0] = a0; dst[HWP] = a1; dst[2 * HWP] = a2; dst[3 * HWP] = a3;
}

// ---------------- GEMM1 (split-K): part[s][n][k][c2] = sum_{p in chunk} t2[k,p]*t6[c2,p] ----
// Tm=128, Tn=128, BK=64; 1D grid 768; XCD swizzle: n % 8 == bid % 8.
__global__ __launch_bounds__(256) void gemm1_kernel(const _Float16* __restrict__ xh,
                                                    const _Float16* __restrict__ p2wh,
                                                    float* __restrict__ part) {
    __shared__ _Float16 As[128 * 72];
    __shared__ _Float16 Bs[128 * 72];

    const int bid   = blockIdx.x;
    const int r8    = bid & 7;
    const int g     = bid >> 3;             // 0..95
    const int n     = r8 + 8 * (g / 24);
    const int inner = g % 24;
    const int m0    = (inner % 3) * 128;    // k base
    const int s     = inner / 3;            // split 0..7
    const int i0    = (s * 49) >> 3;
    const int i1    = ((s + 1) * 49) >> 3;

    const int tid = threadIdx.x;
    const int r   = tid >> 1;               // 0..127
    const int c0  = (tid & 1) * 32;

    const int k   = m0 + r;
    const int ca  = k / 3;
    const int ja  = k - ca * 3;
    const int ashift = 112 * (ja - 1);
    const _Float16* xa = xh + ((size_t)n * CCH + ca) * HWP;
    const _Float16* pw = p2wh + (size_t)k * HWP;
    const _Float16* xb = xh + ((size_t)n * CCH + r) * HWP;

    const int wave = tid >> 6;
    const int lane = tid & 63;
    const int l15  = lane & 15;
    const int quad = lane >> 4;
    const int wm   = (wave >> 1) * 64;
    const int wn   = (wave & 1) * 64;

    floatx4 acc[4][4];
#pragma unroll
    for (int a = 0; a < 4; ++a)
#pragma unroll
        for (int b = 0; b < 4; ++b) acc[a][b] = (floatx4){0.f,0.f,0.f,0.f};

    for (int it = i0; it < i1; ++it) {
        const int p0 = it * 64;
#pragma unroll
        for (int seg = 0; seg < 4; ++seg) {
            const int col = c0 + seg * 8;
            const int pA  = p0 + col;
            // A
            {
                const int srcp = pA + ashift;  // 8-aligned run: wholly in/out of bounds
                half8 prod;
                if (srcp >= 0 && srcp < HWP) {
                    const half8 xv = *(const half8*)(xa + srcp);
                    const half8 wv = *(const half8*)(pw + pA);
                    prod = xv * wv;
                } else {
#pragma unroll
                    for (int i = 0; i < 8; ++i) prod[i] = (_Float16)0.f;
                }
                *(half8*)(&As[r * 72 + col]) = prod;
            }
            // B
            {
                const int proll = (pA >= WWD) ? (pA - WWD) : (pA + (HH - 1) * WWD);
                const half8 u = *(const half8*)(xb + pA);
                const half8 v = *(const half8*)(xb + proll);
                *(half8*)(&Bs[r * 72 + col]) = u + v;
            }
        }
        __syncthreads();
#pragma unroll
        for (int ks = 0; ks < 2; ++ks) {
            const int ko = ks * 32 + quad * 8;
            half8 af[4], bf[4];
#pragma unroll
            for (int mi = 0; mi < 4; ++mi) af[mi] = *(half8*)(&As[(wm + mi * 16 + l15) * 72 + ko]);
#pragma unroll
            for (int ni = 0; ni < 4; ++ni) bf[ni] = *(half8*)(&Bs[(wn + ni * 16 + l15) * 72 + ko]);
#pragma unroll
            for (int mi = 0; mi < 4; ++mi)
#pragma unroll
                for (int ni = 0; ni < 4; ++ni)
                    acc[mi][ni] = __builtin_amdgcn_mfma_f32_16x16x32_f16(af[mi], bf[ni], acc[mi][ni], 0, 0, 0);
        }
        __syncthreads();
    }

    float* pbase = part + (size_t)(s * NB + n) * K3C * CCH;
#pragma unroll
    for (int mi = 0; mi < 4; ++mi)
#pragma unroll
        for (int ni = 0; ni < 4; ++ni) {
            const int kr = m0 + wm + mi * 16 + quad * 4;
            const int cc = wn + ni * 16 + l15;
#pragma unroll
            for (int r2 = 0; r2 < 4; ++r2)
                pbase[(size_t)(kr + r2) * CCH + cc] = acc[mi][ni][r2];
        }
}

// ---------------- reduce: t7T[n][c2][k] = (1/56) * sum_s part[s][n][k][c2] ----------------
__global__ __launch_bounds__(256) void reduce_kernel(const float* __restrict__ part,
                                                     _Float16* __restrict__ t7T) {
    __shared__ _Float16 tile[16][130];
    const int n  = blockIdx.y;
    const int k0 = blockIdx.x * 16;
    const int t  = threadIdx.x;
    const int c2 = t & 127;
    const int kh = t >> 7;
#pragma unroll
    for (int kk = 0; kk < 8; ++kk) {
        const int k = kh * 8 + kk;
        float sum = 0.f;
#pragma unroll
        for (int sp = 0; sp < SPLITK; ++sp)
            sum += part[(((size_t)sp * NB + n) * K3C + k0 + k) * CCH + c2];
        tile[k][c2] = (_Float16)(sum * (1.0f / 56.0f));
    }
    __syncthreads();
    const int kt = t & 15;
    const int c0 = t >> 4;
#pragma unroll
    for (int cc = 0; cc < 8; ++cc) {
        const int cw = c0 * 8 + cc;
        t7T[((size_t)n * CCH + cw) * K3C + k0 + kt] = tile[kt][cw];
    }
}

// ---------------- GEMM2: out[n,c2,p] = t8*x + (1/sqrt(384)) sum_k t7T[c2,k]*t3[k,p] ----------
// Tm=128, Tn=64 p; 1D grid 1568; XCD swizzle: n % 8 == bid % 8 (t7T[n] stays in one L2).
__global__ __launch_bounds__(256) void gemm2_kernel(const _Float16* __restrict__ xh,
                                                    const _Float16* __restrict__ t7T,
                                                    const float* __restrict__ t8,
                                                    float* __restrict__ out) {
    __shared__ _Float16 As[128 * 72];   // [c2][k]
    __shared__ _Float16 Bs[64 * 72];    // [p][k]

    const int bid = blockIdx.x;
    const int r8  = bid & 7;
    const int g   = bid >> 3;           // 0..195
    const int n   = r8 + 8 * (g / 49);
    const int pt0 = (g % 49) * 64;
    const int tid = threadIdx.x;

    const int ar = tid >> 1;
    const int ac = (tid & 1) * 32;
    const _Float16* asrc = t7T + ((size_t)n * CCH + ar) * K3C;

    const int kb = (tid & 15) * 4;
    const int pb = (tid >> 4) * 4;
    const int pg = pt0 + pb;
    const int hB = pg / WWD;
    const int w0 = pg - hB * WWD;       // even
    const _Float16* xnh = xh + (size_t)n * CCH * HWP + hB * WWD;

    const int wave = tid >> 6;
    const int lane = tid & 63;
    const int l15  = lane & 15;
    const int quad = lane >> 4;
    const int wm   = (wave >> 1) * 64;
    const int wn   = (wave & 1) * 32;

    floatx4 acc[4][2];
#pragma unroll
    for (int a = 0; a < 4; ++a)
#pragma unroll
        for (int b = 0; b < 2; ++b) acc[a][b] = (floatx4){0.f,0.f,0.f,0.f};

    for (int k0 = 0; k0 < K3C; k0 += 64) {
        // A
#pragma unroll
        for (int seg = 0; seg < 4; ++seg)
            *(half8*)(&As[ar * 72 + ac + seg * 8]) = *(const half8*)(asrc + k0 + ac + seg * 8);
        // B: t3[k,p] = x[c, h, w + 2j - 2], zero-pad in w
        {
            _Float16 vals[4][4];
#pragma unroll
            for (int kk = 0; kk < 4; ++kk) {
                const int k = k0 + kb + kk;
                const int c = k / 3;
                const int j = k - c * 3;
                const int lo = w0 + 2 * j - 2;   // even
                const _Float16* row = xnh + (size_t)c * HWP;
                if (lo >= 0 && lo + 3 < WWD) {
                    const h4u v = *(const h4u*)(row + lo);
                    vals[kk][0] = v[0]; vals[kk][1] = v[1]; vals[kk][2] = v[2]; vals[kk][3] = v[3];
                } else {
#pragma unroll
                    for (int pp = 0; pp < 4; ++pp) {
                        const int w = lo + pp;
                        vals[kk][pp] = (w >= 0 && w < WWD) ? row[w] : (_Float16)0.f;
                    }
                }
            }
#pragma unroll
            for (int pp = 0; pp < 4; ++pp) {
                half4 col;
                col[0] = vals[0][pp]; col[1] = vals[1][pp];
                col[2] = vals[2][pp]; col[3] = vals[3][pp];
                *(half4*)(&Bs[(pb + pp) * 72 + kb]) = col;
            }
        }
        __syncthreads();
#pragma unroll
        for (int ks = 0; ks < 2; ++ks) {
            const int ko = ks * 32 + quad * 8;
            half8 af[4], bf[2];
#pragma unroll
            for (int mi = 0; mi < 4; ++mi) af[mi] = *(half8*)(&As[(wm + mi * 16 + l15) * 72 + ko]);
#pragma unroll
            for (int ni = 0; ni < 2; ++ni) bf[ni] = *(half8*)(&Bs[(wn + ni * 16 + l15) * 72 + ko]);
#pragma unroll
            for (int mi = 0; mi < 4; ++mi)
#pragma unroll
                for (int ni = 0; ni < 2; ++ni)
                    acc[mi][ni] = __builtin_amdgcn_mfma_f32_16x16x32_f16(af[mi], bf[ni], acc[mi][ni], 0, 0, 0);
        }
        __syncthreads();
    }

    const float sc = 0.05103103630798288f;  // 1/sqrt(384)
#pragma unroll
    for (int mi = 0; mi < 4; ++mi)
#pragma unroll
        for (int ni = 0; ni < 2; ++ni) {
            const int ccb = wm + mi * 16 + quad * 4;
            const int pp  = pt0 + wn + ni * 16 + l15;
#pragma unroll
            for (int r2 = 0; r2 < 4; ++r2) {
                const int c2 = ccb + r2;
                const size_t oidx = ((size_t)n * CCH + c2) * HWP + pp;
                const float t9 = t8[((size_t)n * 4 + (c2 & 3)) * HWP + pp] * (float)xh[oidx];
                out[oidx] = acc[mi][ni][r2] * sc + t9;
            }
        }
}

extern "C" void kernel_launch(void* const* d_in, const int* in_sizes, int n_in,
                              void* d_out, int out_size, void* d_ws, size_t ws_size,
                              hipStream_t stream) {
    const float* x      = (const float*)d_in[0];
    const float* p2w    = (const float*)d_in[1];
    const float* p5w    = (const float*)d_in[2];
    const float* conv_w = (const float*)d_in[3];
    float* out = (float*)d_out;

    // ws layout: x_h (25.69 MB) | p2w_h (2.41 MB) | t8 f32 (1.61 MB) | t7T f16 (3.15 MB)
    char* ws = (char*)d_ws;
    _Float16* xh   = (_Float16*)ws;
    _Float16* p2wh = (_Float16*)(ws + 25690112);
    float*    t8f  = (float*)   (ws + 25690112 + 2408448);
    _Float16* t7T  = (_Float16*)(ws + 25690112 + 2408448 + 1605632);
    float*    part = out;  // 12.58M f32 <= 12.85M; consumed by reduce before gemm2 writes

    cvt_kernel<<<dim3(6272), dim3(256), 0, stream>>>(x, xh);
    cvt_kernel<<<dim3(588), dim3(256), 0, stream>>>(p2w, p2wh);
    t8_kernel<<<dim3(1568), dim3(64), 0, stream>>>(xh, conv_w, p5w, t8f);
    gemm1_kernel<<<dim3(768), dim3(256), 0, stream>>>(xh, p2wh, part);
    reduce_kernel<<<dim3(24, NB), dim3(256), 0, stream>>>(part, t7T);
    gemm2_kernel<<<dim3(1568), dim3(256), 0, stream>>>(xh, t7T, t8f, out);
}